// Round 8
// baseline (91.722 us; speedup 1.0000x reference)
//
#include <hip/hip_runtime.h>
#include <hip/hip_bf16.h>
#include <math.h>

#define B 4
#define T 128
#define S 512
#define H 512
// 2*log2(e): folds tanh's 2x and e->2 base change into the projection epilogue
#define QK_SCALE 2.8853900817779268f

// Hardware exp2 (v_exp_f32). Fallback = native exp path, never OCML-precise.
#if defined(__has_builtin)
#if __has_builtin(__builtin_amdgcn_exp2f)
#define EXP2F(x) __builtin_amdgcn_exp2f(x)
#else
#define EXP2F(x) __expf((x) * 0.6931471805599453f)
#endif
#else
#define EXP2F(x) __expf((x) * 0.6931471805599453f)
#endif

typedef __attribute__((ext_vector_type(8))) short bf16x8;
typedef __attribute__((ext_vector_type(4))) float f32x4;

__device__ __forceinline__ short f2b(float x) {   // f32 -> bf16 RNE
    unsigned int u = __float_as_uint(x);
    u += 0x7fffu + ((u >> 16) & 1u);
    return (short)(u >> 16);
}
__device__ __forceinline__ float fast_tanh(float x) {
    float e = __expf(2.0f * x);
    float r = __builtin_amdgcn_rcpf(e + 1.0f);
    return 1.0f - 2.0f * r;
}
// load 8 f32 and convert to a bf16x8 MFMA fragment (RNE, same as cvt_all did)
__device__ __forceinline__ bf16x8 ld_cvt8(const float* p) {
    float4 a = *(const float4*)p;
    float4 c = *(const float4*)(p + 4);
    bf16x8 r;
    r[0] = f2b(a.x); r[1] = f2b(a.y); r[2] = f2b(a.z); r[3] = f2b(a.w);
    r[4] = f2b(c.x); r[5] = f2b(c.y); r[6] = f2b(c.z); r[7] = f2b(c.w);
    return r;
}

#define MFMA_STEP(A0, A1, B0, B1)                                                \
    {                                                                            \
        acc00 = __builtin_amdgcn_mfma_f32_16x16x32_bf16(A0, B0, acc00, 0, 0, 0); \
        acc01 = __builtin_amdgcn_mfma_f32_16x16x32_bf16(A0, B1, acc01, 0, 0, 0); \
        acc10 = __builtin_amdgcn_mfma_f32_16x16x32_bf16(A1, B0, acc10, 0, 0, 0); \
        acc11 = __builtin_amdgcn_mfma_f32_16x16x32_bf16(A1, B1, acc11, 0, 0, 0); \
    }

// ---- phase 1: fused projections (inline f32->bf16 cvt), Eq/Ek = exp2(GEMM*2log2e)
// exp factorization: exp2(q~+k~) = Eq*Ek, so score needs no exp.
// k-part blocks with s0 >= L are skipped (their ke rows are never read).
__global__ __launch_bounds__(64) void mfma_proj(
    const float* __restrict__ query, const float* __restrict__ enc,
    const float* __restrict__ Ws, const float* __restrict__ Wh,
    const int* __restrict__ slen, float* __restrict__ qe, float* __restrict__ ke) {
    const int lane = threadIdx.x;
    const int r = lane & 15, kb = lane >> 4;
    const int n0 = blockIdx.x * 32;
    const int m0 = blockIdx.y * 32;
    const float* A; const float* W; float* C;
    if (m0 < 512) { A = query + (size_t)m0 * H; W = Ws; C = qe + (size_t)m0 * H; }
    else {
        const int row = m0 - 512;
        if ((row & 511) >= slen[row >> 9]) return;   // masked k-rows: dead work
        A = enc + (size_t)row * H; W = Wh; C = ke + (size_t)row * H;
    }
    const float* a0p = A + (size_t)r * H + kb * 8;
    const float* a1p = a0p + 16 * H;
    const float* b0p = W + (size_t)(n0 + r) * H + kb * 8;
    const float* b1p = b0p + 16 * H;
    f32x4 acc00 = {0,0,0,0}, acc01 = {0,0,0,0}, acc10 = {0,0,0,0}, acc11 = {0,0,0,0};
#pragma unroll 4
    for (int k = 0; k < H; k += 32) {
        bf16x8 a0 = ld_cvt8(a0p + k), a1 = ld_cvt8(a1p + k);
        bf16x8 b0 = ld_cvt8(b0p + k), b1 = ld_cvt8(b1p + k);
        MFMA_STEP(a0, a1, b0, b1)
    }
    const int cr = kb * 4, cc = r;
#pragma unroll
    for (int g = 0; g < 4; ++g) {
        C[(size_t)(cr + g) * H + n0 + cc]           = EXP2F(acc00[g] * QK_SCALE);
        C[(size_t)(cr + g) * H + n0 + 16 + cc]      = EXP2F(acc01[g] * QK_SCALE);
        C[(size_t)(16 + cr + g) * H + n0 + cc]      = EXP2F(acc10[g] * QK_SCALE);
        C[(size_t)(16 + cr + g) * H + n0 + 16 + cc] = EXP2F(acc11[g] * QK_SCALE);
    }
}

// ---- phase 2: partial score over one h-quarter (128 h), 8t x 16s per wave ----
// scoreh[qt][b*T+t][s] = -sum_h 2 v[h] * rcp(Eq[t,h]*Ek[s,h] + 1)
__global__ __launch_bounds__(64) void score_v4(
    const float* __restrict__ qe, const float* __restrict__ ke,
    const float* __restrict__ v, const int* __restrict__ slen,
    float* __restrict__ scoreh) {
    const int qt = blockIdx.z & 3;
    const int b = blockIdx.z >> 2;
    const int L = slen[b];
    const int sbase = blockIdx.x * 16;
    if (sbase >= L) return;
    const int tbase = blockIdx.y * 8;
    const int hbase = qt * 128;
    // stride 132 f32: row r base bank = 4r mod 32; b128 reads 2-way max (free)
    __shared__ __align__(16) float qs[8][132];
    __shared__ __align__(16) float ks[16][132];
    __shared__ __align__(16) float vsh[128];
    const int lane = threadIdx.x;
    {   // staging: q row r=lane>>3 (4 float4), k rows r and r+8 (8 float4)
        const int r = lane >> 3, c = (lane & 7) * 16;
        const float* qsrc = qe + (size_t)(b * T + tbase + r) * H + hbase + c;
        const float* k0src = ke + (size_t)(b * S + sbase + r) * H + hbase + c;
        const float* k1src = k0src + 8 * H;
#pragma unroll
        for (int j = 0; j < 4; ++j) {
            *(float4*)&qs[r][c + j * 4] = *(const float4*)(qsrc + j * 4);
            *(float4*)&ks[r][c + j * 4] = *(const float4*)(k0src + j * 4);
            *(float4*)&ks[8 + r][c + j * 4] = *(const float4*)(k1src + j * 4);
        }
        float2 vv = *(const float2*)&v[hbase + lane * 2];
        *(float2*)&vsh[lane * 2] = make_float2(-2.f * vv.x, -2.f * vv.y);
    }
    __syncthreads();
    const int t = lane >> 3, s0 = (lane & 7) * 2;
    const float* qrow = &qs[t][0];
    const float* k0r = &ks[s0][0];
    const float* k1r = &ks[s0 + 1][0];
    float a0 = 0.f, a1 = 0.f, c0 = 0.f, c1 = 0.f;
#pragma unroll 2
    for (int i = 0; i < 128; i += 4) {   // per elem: fma, rcp, fma
        float4 q4 = *(const float4*)&qrow[i];
        float4 ka = *(const float4*)&k0r[i];
        float4 kb = *(const float4*)&k1r[i];
        float4 v4 = *(const float4*)&vsh[i];
        a0 = fmaf(v4.x, __builtin_amdgcn_rcpf(fmaf(q4.x, ka.x, 1.f)), a0);
        c0 = fmaf(v4.x, __builtin_amdgcn_rcpf(fmaf(q4.x, kb.x, 1.f)), c0);
        a1 = fmaf(v4.y, __builtin_amdgcn_rcpf(fmaf(q4.y, ka.y, 1.f)), a1);
        c1 = fmaf(v4.y, __builtin_amdgcn_rcpf(fmaf(q4.y, kb.y, 1.f)), c1);
        a0 = fmaf(v4.z, __builtin_amdgcn_rcpf(fmaf(q4.z, ka.z, 1.f)), a0);
        c0 = fmaf(v4.z, __builtin_amdgcn_rcpf(fmaf(q4.z, kb.z, 1.f)), c0);
        a1 = fmaf(v4.w, __builtin_amdgcn_rcpf(fmaf(q4.w, ka.w, 1.f)), a1);
        c1 = fmaf(v4.w, __builtin_amdgcn_rcpf(fmaf(q4.w, kb.w, 1.f)), c1);
    }
    *(float2*)&scoreh[((size_t)qt * (B * T) + b * T + tbase + t) * S + sbase + s0] =
        make_float2(a0 + a1, c0 + c1);
}

// ---- phase 3: fused {softmax over 4 slices -> bf16 attn} + {encT transpose} ----
__global__ __launch_bounds__(256) void mid_kernel(
    const float* __restrict__ scoreh, const int* __restrict__ slen,
    short* __restrict__ attnb, const float* __restrict__ enc,
    short* __restrict__ encT) {
    __shared__ short tb[32][33];
    __shared__ float red[8];
    const int bid = blockIdx.x;
    const int tid = threadIdx.x;
    if (bid >= 512) {   // encT[b][h][s] = bf16(enc[b][s][h])
        const int bid2 = bid - 512;
        const int b = bid2 >> 8, s0 = ((bid2 >> 4) & 15) * 32, h0 = (bid2 & 15) * 32;
        const int r = tid >> 3, c = (tid & 7) * 4;
        float4 a = *(const float4*)&enc[((size_t)(b * S + s0 + r)) * H + h0 + c];
        tb[c + 0][r] = f2b(a.x); tb[c + 1][r] = f2b(a.y);
        tb[c + 2][r] = f2b(a.z); tb[c + 3][r] = f2b(a.w);
        __syncthreads();
        ushort4 o = make_ushort4((unsigned short)tb[r][c], (unsigned short)tb[r][c + 1],
                                 (unsigned short)tb[r][c + 2], (unsigned short)tb[r][c + 3]);
        *(ushort4*)&encT[((size_t)(b * H + h0 + r)) * S + s0 + c] = o;
        return;
    }
    const int row = bid;                 // 0..511
    const int L = slen[row >> 7];        // T = 128
    const int lane = tid & 63, wv = tid >> 6;
    const size_t sl = (size_t)(B * T) * S;
    const float* p0 = scoreh + (size_t)row * S;
    float x0 = p0[tid] + p0[sl + tid] + p0[2 * sl + tid] + p0[3 * sl + tid];
    float x1 = p0[tid + 256] + p0[sl + tid + 256] + p0[2 * sl + tid + 256] +
               p0[3 * sl + tid + 256];
    if (tid >= L) x0 = -INFINITY;
    if (tid + 256 >= L) x1 = -INFINITY;
    float m = fmaxf(x0, x1);
#pragma unroll
    for (int off = 32; off > 0; off >>= 1) m = fmaxf(m, __shfl_xor(m, off));
    if (lane == 0) red[wv] = m;
    __syncthreads();
    m = fmaxf(fmaxf(red[0], red[1]), fmaxf(red[2], red[3]));
    float e0 = __expf(x0 - m);   // masked -inf -> 0
    float e1 = __expf(x1 - m);
    float sm = e0 + e1;
#pragma unroll
    for (int off = 32; off > 0; off >>= 1) sm += __shfl_xor(sm, off);
    if (lane == 0) red[4 + wv] = sm;
    __syncthreads();
    float inv = 1.0f / (red[4] + red[5] + red[6] + red[7]);
    short* o = attnb + (size_t)row * S;
    o[tid] = f2b(e0 * inv);
    o[tid + 256] = f2b(e1 * inv);
}

// ---- phase 4: ctx = attn @ enc (K capped at ceil(L/32)*32; masked attn == 0) ----
__global__ __launch_bounds__(64) void mfma_ctx(
    const short* __restrict__ attnb, const short* __restrict__ encT,
    const int* __restrict__ slen, short* __restrict__ ctxb) {
    const int b = blockIdx.z;
    const int L = slen[b];
    const int Keff = min(S, (L + 31) & ~31);
    const int lane = threadIdx.x;
    const int r = lane & 15, kb = lane >> 4;
    const int m0 = blockIdx.y * 32;
    const int n0 = blockIdx.x * 32;
    const short* A = attnb + (size_t)(b * T + m0) * S;
    const short* Bp = encT + (size_t)b * H * S;
    const short* a0p = A + (size_t)r * S + kb * 8;
    const short* a1p = a0p + 16 * S;
    const short* b0p = Bp + (size_t)(n0 + r) * S + kb * 8;
    const short* b1p = b0p + 16 * S;
    f32x4 acc00 = {0,0,0,0}, acc01 = {0,0,0,0}, acc10 = {0,0,0,0}, acc11 = {0,0,0,0};
#pragma unroll 2
    for (int k = 0; k < Keff; k += 32) {
        bf16x8 a0 = *(const bf16x8*)(a0p + k), a1 = *(const bf16x8*)(a1p + k);
        bf16x8 b0 = *(const bf16x8*)(b0p + k), b1 = *(const bf16x8*)(b1p + k);
        MFMA_STEP(a0, a1, b0, b1)
    }
    const int cr = kb * 4, cc = r;
#pragma unroll
    for (int g = 0; g < 4; ++g) {
        size_t row0 = (size_t)(b * T + m0 + cr + g) * H;
        size_t row1 = (size_t)(b * T + m0 + 16 + cr + g) * H;
        ctxb[row0 + n0 + cc]      = f2b(acc00[g]);
        ctxb[row0 + n0 + 16 + cc] = f2b(acc01[g]);
        ctxb[row1 + n0 + cc]      = f2b(acc10[g]);
        ctxb[row1 + n0 + 16 + cc] = f2b(acc11[g]);
    }
}

// ---- phase 5: pre = tanh([ctx|query] @ W_out^T + b)  (query/W_out inline cvt) ----
__global__ __launch_bounds__(64) void mfma_out(
    const short* __restrict__ ctxb, const float* __restrict__ query,
    const float* __restrict__ Wo, const float* __restrict__ bias,
    float* __restrict__ pre) {
    const int lane = threadIdx.x;
    const int r = lane & 15, kb = lane >> 4;
    const int m0 = blockIdx.y * 32, n0 = blockIdx.x * 32;
    f32x4 acc00 = {0,0,0,0}, acc01 = {0,0,0,0}, acc10 = {0,0,0,0}, acc11 = {0,0,0,0};
    const float* b0p = Wo + (size_t)(n0 + r) * (2 * H) + kb * 8;
    const float* b1p = b0p + 16 * (2 * H);
    {   // K 0..511: ctx (bf16)
        const short* a0p = ctxb + (size_t)(m0 + r) * H + kb * 8;
        const short* a1p = a0p + 16 * H;
#pragma unroll 4
        for (int k = 0; k < H; k += 32) {
            bf16x8 a0 = *(const bf16x8*)(a0p + k), a1 = *(const bf16x8*)(a1p + k);
            bf16x8 b0 = ld_cvt8(b0p + k), b1 = ld_cvt8(b1p + k);
            MFMA_STEP(a0, a1, b0, b1)
        }
    }
    {   // K 512..1023: query (f32, inline cvt)
        const float* a0p = query + (size_t)(m0 + r) * H + kb * 8;
        const float* a1p = a0p + 16 * H;
        const float* c0p = b0p + H;
        const float* c1p = b1p + H;
#pragma unroll 4
        for (int k = 0; k < H; k += 32) {
            bf16x8 a0 = ld_cvt8(a0p + k), a1 = ld_cvt8(a1p + k);
            bf16x8 b0 = ld_cvt8(c0p + k), b1 = ld_cvt8(c1p + k);
            MFMA_STEP(a0, a1, b0, b1)
        }
    }
    const int cr = kb * 4, cc = r;
    float bn0 = bias[n0 + cc], bn1 = bias[n0 + 16 + cc];
#pragma unroll
    for (int g = 0; g < 4; ++g) {
        size_t row0 = (size_t)(m0 + cr + g) * H;
        size_t row1 = (size_t)(m0 + 16 + cr + g) * H;
        pre[row0 + n0 + cc]      = fast_tanh(acc00[g] + bn0);
        pre[row0 + n0 + 16 + cc] = fast_tanh(acc01[g] + bn1);
        pre[row1 + n0 + cc]      = fast_tanh(acc10[g] + bn0);
        pre[row1 + n0 + 16 + cc] = fast_tanh(acc11[g] + bn1);
    }
}

// ---- phase 6: per-row LayerNorm ----
__global__ __launch_bounds__(256) void ln_out(
    const float* __restrict__ X, const float* __restrict__ gamma,
    const float* __restrict__ beta, float* __restrict__ out) {
    __shared__ float red[8];
    const int r = blockIdx.x;
    const int tid = threadIdx.x;
    const int lane = tid & 63, wv = tid >> 6;
    const float* x = X + (size_t)r * H;
    float x0 = x[tid], x1 = x[tid + 256];
    float s = x0 + x1;
#pragma unroll
    for (int off = 32; off > 0; off >>= 1) s += __shfl_down(s, off);
    if (lane == 0) red[wv] = s;
    __syncthreads();
    float mu = (red[0] + red[1] + red[2] + red[3]) * (1.0f / H);
    float d0 = x0 - mu, d1 = x1 - mu;
    float vsum = d0 * d0 + d1 * d1;
#pragma unroll
    for (int off = 32; off > 0; off >>= 1) vsum += __shfl_down(vsum, off);
    if (lane == 0) red[4 + wv] = vsum;
    __syncthreads();
    float var = (red[4] + red[5] + red[6] + red[7]) * (1.0f / H);
    float inv = rsqrtf(var + 1e-5f);
    out[(size_t)r * H + tid] = d0 * inv * gamma[tid] + beta[tid];
    out[(size_t)r * H + tid + 256] = d1 * inv * gamma[tid + 256] + beta[tid + 256];
}

extern "C" void kernel_launch(void* const* d_in, const int* in_sizes, int n_in,
                              void* d_out, int out_size, void* d_ws, size_t ws_size,
                              hipStream_t stream) {
    const float* query = (const float*)d_in[0];
    const float* enc   = (const float*)d_in[1];
    const int*   slen  = (const int*)d_in[2];
    const float* W_h   = (const float*)d_in[3];
    const float* W_s   = (const float*)d_in[4];
    const float* v     = (const float*)d_in[5];
    const float* W_out = (const float*)d_in[6];
    const float* b_out = (const float*)d_in[7];
    const float* gamma = (const float*)d_in[8];
    const float* beta  = (const float*)d_in[9];
    float* out = (float*)d_out;

    // ---- workspace map, non-aliased (d_ws = 256 MB per R6 profile) ----
    char* base = (char*)d_ws;
    float* qe     = (float*)(base + 0);          // 1M    f32 exp2(q_proj~)
    float* ke     = (float*)(base + 1048576);    // 4M    f32 exp2(k_proj~)
    float* scoreh = (float*)(base + 5242880);    // 4M    f32 score quarters
    short* attnb  = (short*)(base + 9437184);    // 512K  bf16 attn
    short* encT   = (short*)(base + 9961472);    // 2M    bf16 enc^T
    short* ctxb   = (short*)(base + 12058624);   // 512K  bf16 ctx
    float* pre    = (float*)(base + 12582912);   // 1M    f32 pre-LN

    mfma_proj<<<dim3(16, 80), dim3(64), 0, stream>>>(query, enc, W_s, W_h, slen, qe, ke);
    // score quarters: grid (s-tiles=32, t-tiles=16, b*4 quarters=16)
    score_v4<<<dim3(32, 16, 16), dim3(64), 0, stream>>>(qe, ke, v, slen, scoreh);
    // fused softmax (blocks 0..511) + encT transpose (blocks 512..1535)
    mid_kernel<<<dim3(1536), dim3(256), 0, stream>>>(scoreh, slen, attnb, enc, encT);
    mfma_ctx<<<dim3(16, 4, 4), dim3(64), 0, stream>>>(attnb, encT, slen, ctxb);
    mfma_out<<<dim3(16, 16), dim3(64), 0, stream>>>(ctxb, query, W_out, b_out, pre);
    ln_out<<<dim3(B * T), dim3(256), 0, stream>>>(pre, gamma, beta, out);
}

// Round 9
// 65.595 us; speedup vs baseline: 1.3983x; 1.3983x over previous
//
#include <hip/hip_runtime.h>
#include <hip/hip_bf16.h>
#include <math.h>

#define B 4
#define T 128
#define S 512
#define H 512
// 2*log2(e): folds tanh's 2x and e->2 base change into the projection epilogue
#define QK_SCALE 2.8853900817779268f

// Hardware exp2 (v_exp_f32). Fallback = native exp path, never OCML-precise.
#if defined(__has_builtin)
#if __has_builtin(__builtin_amdgcn_exp2f)
#define EXP2F(x) __builtin_amdgcn_exp2f(x)
#else
#define EXP2F(x) __expf((x) * 0.6931471805599453f)
#endif
#else
#define EXP2F(x) __expf((x) * 0.6931471805599453f)
#endif

typedef __attribute__((ext_vector_type(8))) short bf16x8;
typedef __attribute__((ext_vector_type(4))) float f32x4;

__device__ __forceinline__ short f2b(float x) {   // f32 -> bf16 RNE
    unsigned int u = __float_as_uint(x);
    u += 0x7fffu + ((u >> 16) & 1u);
    return (short)(u >> 16);
}
__device__ __forceinline__ float fast_tanh(float x) {
    float e = __expf(2.0f * x);
    float r = __builtin_amdgcn_rcpf(e + 1.0f);
    return 1.0f - 2.0f * r;
}

// ---- phase 1: cvt inputs to bf16 (blocks 0..1151) + encT transpose (1152..2175) ----
// bf16 staging doubles as L2 prefetch/compaction for the latency-bound MFMA
// kernels (R8 lesson: inline f32 cvt in 1-wave/CU GEMMs = cold-HBM serial loads).
__global__ __launch_bounds__(256) void cvt_all(
    const float* __restrict__ q, const float* __restrict__ Ws,
    const float* __restrict__ Wh, const float* __restrict__ Wo,
    const float* __restrict__ enc, const int* __restrict__ slen,
    short* __restrict__ qb, short* __restrict__ wsb, short* __restrict__ whb,
    short* __restrict__ wob, short* __restrict__ eb, short* __restrict__ encT) {
    const int bid = blockIdx.x;
    const int tid = threadIdx.x;
    if (bid >= 1152) {   // encT[b][h][s] = bf16(enc[b][s][h])
        __shared__ short tb[32][33];
        const int bid2 = bid - 1152;
        const int b = bid2 >> 8, s0 = ((bid2 >> 4) & 15) * 32, h0 = (bid2 & 15) * 32;
        if (s0 >= slen[b]) return;   // cols >= ceil32(L) never read by mfma_ctx
        const int r = tid >> 3, c = (tid & 7) * 4;
        float4 a = *(const float4*)&enc[((size_t)(b * S + s0 + r)) * H + h0 + c];
        tb[c + 0][r] = f2b(a.x); tb[c + 1][r] = f2b(a.y);
        tb[c + 2][r] = f2b(a.z); tb[c + 3][r] = f2b(a.w);
        __syncthreads();
        ushort4 o = make_ushort4((unsigned short)tb[r][c], (unsigned short)tb[r][c + 1],
                                 (unsigned short)tb[r][c + 2], (unsigned short)tb[r][c + 3]);
        *(ushort4*)&encT[((size_t)(b * H + h0 + r)) * S + s0 + c] = o;
        return;
    }
    size_t i = ((size_t)bid * 256 + tid) * 8;
    const float* src; short* dst; size_t off;
    if (i < 262144)        { src = q;   dst = qb;  off = i; }
    else if (i < 524288)   { src = Ws;  dst = wsb; off = i - 262144; }
    else if (i < 786432)   { src = Wh;  dst = whb; off = i - 524288; }
    else if (i < 1310720)  { src = Wo;  dst = wob; off = i - 786432; }
    else                   { src = enc; dst = eb;  off = i - 1310720; }
    float4 a = *(const float4*)(src + off);
    float4 b = *(const float4*)(src + off + 4);
    ushort4 o0 = make_ushort4((unsigned short)f2b(a.x), (unsigned short)f2b(a.y),
                              (unsigned short)f2b(a.z), (unsigned short)f2b(a.w));
    ushort4 o1 = make_ushort4((unsigned short)f2b(b.x), (unsigned short)f2b(b.y),
                              (unsigned short)f2b(b.z), (unsigned short)f2b(b.w));
    *(ushort4*)(dst + off) = o0;
    *(ushort4*)(dst + off + 4) = o1;
}

// ---- MFMA wave-GEMM core: 32x32 per wave, direct global bf16 loads ----
#define MFMA4(APTR0, APTR1, BPTR0, BPTR1, KOFF)                                  \
    {                                                                            \
        bf16x8 a0 = *(const bf16x8*)((APTR0) + (KOFF));                          \
        bf16x8 a1 = *(const bf16x8*)((APTR1) + (KOFF));                          \
        bf16x8 b0 = *(const bf16x8*)((BPTR0) + (KOFF));                          \
        bf16x8 b1 = *(const bf16x8*)((BPTR1) + (KOFF));                          \
        acc00 = __builtin_amdgcn_mfma_f32_16x16x32_bf16(a0, b0, acc00, 0, 0, 0); \
        acc01 = __builtin_amdgcn_mfma_f32_16x16x32_bf16(a0, b1, acc01, 0, 0, 0); \
        acc10 = __builtin_amdgcn_mfma_f32_16x16x32_bf16(a1, b0, acc10, 0, 0, 0); \
        acc11 = __builtin_amdgcn_mfma_f32_16x16x32_bf16(a1, b1, acc11, 0, 0, 0); \
    }

// ---- phase 2: fused projections, Eq/Ek = exp2(GEMM * 2log2e)  (f32 out) ----
// exp factorization: exp2(q~+k~) = Eq*Ek -> score needs no exp.
// k-tiles whose 32 rows are all masked (row%512 >= L) are skipped.
__global__ __launch_bounds__(64) void mfma_proj(
    const short* __restrict__ qb, const short* __restrict__ eb,
    const short* __restrict__ wsb, const short* __restrict__ whb,
    const int* __restrict__ slen, float* __restrict__ qe, float* __restrict__ ke) {
    const int lane = threadIdx.x;
    const int r = lane & 15, kb = lane >> 4;
    const int n0 = blockIdx.x * 32;
    const int m0 = blockIdx.y * 32;
    const short* A; const short* W; float* C;
    if (m0 < 512) { A = qb + (size_t)m0 * H; W = wsb; C = qe + (size_t)m0 * H; }
    else {
        const int row = m0 - 512;
        if ((row & 511) >= slen[row >> 9]) return;   // fully-masked k-tile
        A = eb + (size_t)row * H; W = whb; C = ke + (size_t)row * H;
    }
    const short* a0p = A + (size_t)r * H + kb * 8;
    const short* a1p = a0p + 16 * H;
    const short* b0p = W + (size_t)(n0 + r) * H + kb * 8;
    const short* b1p = b0p + 16 * H;
    f32x4 acc00 = {0,0,0,0}, acc01 = {0,0,0,0}, acc10 = {0,0,0,0}, acc11 = {0,0,0,0};
#pragma unroll 4
    for (int k = 0; k < H; k += 32) MFMA4(a0p, a1p, b0p, b1p, k)
    const int cr = kb * 4, cc = r;
#pragma unroll
    for (int g = 0; g < 4; ++g) {
        C[(size_t)(cr + g) * H + n0 + cc]           = EXP2F(acc00[g] * QK_SCALE);
        C[(size_t)(cr + g) * H + n0 + 16 + cc]      = EXP2F(acc01[g] * QK_SCALE);
        C[(size_t)(16 + cr + g) * H + n0 + cc]      = EXP2F(acc10[g] * QK_SCALE);
        C[(size_t)(16 + cr + g) * H + n0 + 16 + cc] = EXP2F(acc11[g] * QK_SCALE);
    }
}

// ---- phase 3: partial score over one h-quarter (128 h), 8t x 16s per wave ----
// scoreh[qt][b*T+t][s] = -sum_h 2 v[h] * rcp(Eq[t,h]*Ek[s,h] + 1)
__global__ __launch_bounds__(64) void score_v4(
    const float* __restrict__ qe, const float* __restrict__ ke,
    const float* __restrict__ v, const int* __restrict__ slen,
    float* __restrict__ scoreh) {
    const int qt = blockIdx.z & 3;
    const int b = blockIdx.z >> 2;
    const int L = slen[b];
    const int sbase = blockIdx.x * 16;
    if (sbase >= L) return;
    const int tbase = blockIdx.y * 8;
    const int hbase = qt * 128;
    // stride 132 f32: row r base bank = 4r mod 32; b128 reads 2-way max (free)
    __shared__ __align__(16) float qs[8][132];
    __shared__ __align__(16) float ks[16][132];
    __shared__ __align__(16) float vsh[128];
    const int lane = threadIdx.x;
    {   // staging: q row r=lane>>3 (4 float4), k rows r and r+8 (8 float4)
        const int r = lane >> 3, c = (lane & 7) * 16;
        const float* qsrc = qe + (size_t)(b * T + tbase + r) * H + hbase + c;
        const float* k0src = ke + (size_t)(b * S + sbase + r) * H + hbase + c;
        const float* k1src = k0src + 8 * H;
#pragma unroll
        for (int j = 0; j < 4; ++j) {
            *(float4*)&qs[r][c + j * 4] = *(const float4*)(qsrc + j * 4);
            *(float4*)&ks[r][c + j * 4] = *(const float4*)(k0src + j * 4);
            *(float4*)&ks[8 + r][c + j * 4] = *(const float4*)(k1src + j * 4);
        }
        float2 vv = *(const float2*)&v[hbase + lane * 2];
        *(float2*)&vsh[lane * 2] = make_float2(-2.f * vv.x, -2.f * vv.y);
    }
    __syncthreads();
    const int t = lane >> 3, s0 = (lane & 7) * 2;
    const float* qrow = &qs[t][0];
    const float* k0r = &ks[s0][0];
    const float* k1r = &ks[s0 + 1][0];
    float a0 = 0.f, a1 = 0.f, c0 = 0.f, c1 = 0.f;
#pragma unroll 2
    for (int i = 0; i < 128; i += 4) {   // per elem: fma, rcp, fma
        float4 q4 = *(const float4*)&qrow[i];
        float4 ka = *(const float4*)&k0r[i];
        float4 kb = *(const float4*)&k1r[i];
        float4 v4 = *(const float4*)&vsh[i];
        a0 = fmaf(v4.x, __builtin_amdgcn_rcpf(fmaf(q4.x, ka.x, 1.f)), a0);
        c0 = fmaf(v4.x, __builtin_amdgcn_rcpf(fmaf(q4.x, kb.x, 1.f)), c0);
        a1 = fmaf(v4.y, __builtin_amdgcn_rcpf(fmaf(q4.y, ka.y, 1.f)), a1);
        c1 = fmaf(v4.y, __builtin_amdgcn_rcpf(fmaf(q4.y, kb.y, 1.f)), c1);
        a0 = fmaf(v4.z, __builtin_amdgcn_rcpf(fmaf(q4.z, ka.z, 1.f)), a0);
        c0 = fmaf(v4.z, __builtin_amdgcn_rcpf(fmaf(q4.z, kb.z, 1.f)), c0);
        a1 = fmaf(v4.w, __builtin_amdgcn_rcpf(fmaf(q4.w, ka.w, 1.f)), a1);
        c1 = fmaf(v4.w, __builtin_amdgcn_rcpf(fmaf(q4.w, kb.w, 1.f)), c1);
    }
    *(float2*)&scoreh[((size_t)qt * (B * T) + b * T + tbase + t) * S + sbase + s0] =
        make_float2(a0 + a1, c0 + c1);
}

// ---- phase 4: masked softmax over 4 partial slices, writes bf16 attn ----
__global__ __launch_bounds__(256) void softmax_k(
    const float* __restrict__ scoreh, const int* __restrict__ slen,
    short* __restrict__ attnb) {
    __shared__ float red[8];
    const int row = blockIdx.x;          // 0..511
    const int L = slen[row >> 7];        // T = 128
    const int tid = threadIdx.x;
    const int lane = tid & 63, wv = tid >> 6;
    const size_t sl = (size_t)(B * T) * S;
    const float* p0 = scoreh + (size_t)row * S;
    float x0 = p0[tid] + p0[sl + tid] + p0[2 * sl + tid] + p0[3 * sl + tid];
    float x1 = p0[tid + 256] + p0[sl + tid + 256] + p0[2 * sl + tid + 256] +
               p0[3 * sl + tid + 256];
    if (tid >= L) x0 = -INFINITY;
    if (tid + 256 >= L) x1 = -INFINITY;
    float m = fmaxf(x0, x1);
#pragma unroll
    for (int off = 32; off > 0; off >>= 1) m = fmaxf(m, __shfl_xor(m, off));
    if (lane == 0) red[wv] = m;
    __syncthreads();
    m = fmaxf(fmaxf(red[0], red[1]), fmaxf(red[2], red[3]));
    float e0 = __expf(x0 - m);   // masked -inf -> 0
    float e1 = __expf(x1 - m);
    float sm = e0 + e1;
#pragma unroll
    for (int off = 32; off > 0; off >>= 1) sm += __shfl_xor(sm, off);
    if (lane == 0) red[4 + wv] = sm;
    __syncthreads();
    float inv = 1.0f / (red[4] + red[5] + red[6] + red[7]);
    short* o = attnb + (size_t)row * S;
    o[tid] = f2b(e0 * inv);
    o[tid + 256] = f2b(e1 * inv);
}

// ---- phase 5: ctx = attn @ enc (K capped at ceil(L/32)*32; masked attn == 0) ----
__global__ __launch_bounds__(64) void mfma_ctx(
    const short* __restrict__ attnb, const short* __restrict__ encT,
    const int* __restrict__ slen, short* __restrict__ ctxb) {
    const int b = blockIdx.z;
    const int L = slen[b];
    const int Keff = min(S, (L + 31) & ~31);
    const int lane = threadIdx.x;
    const int r = lane & 15, kb = lane >> 4;
    const int m0 = blockIdx.y * 32;
    const int n0 = blockIdx.x * 32;
    const short* A = attnb + (size_t)(b * T + m0) * S;
    const short* Bp = encT + (size_t)b * H * S;
    const short* a0p = A + (size_t)r * S + kb * 8;
    const short* a1p = a0p + 16 * S;
    const short* b0p = Bp + (size_t)(n0 + r) * S + kb * 8;
    const short* b1p = b0p + 16 * S;
    f32x4 acc00 = {0,0,0,0}, acc01 = {0,0,0,0}, acc10 = {0,0,0,0}, acc11 = {0,0,0,0};
#pragma unroll 2
    for (int k = 0; k < Keff; k += 32) MFMA4(a0p, a1p, b0p, b1p, k)
    const int cr = kb * 4, cc = r;
#pragma unroll
    for (int g = 0; g < 4; ++g) {
        size_t row0 = (size_t)(b * T + m0 + cr + g) * H;
        size_t row1 = (size_t)(b * T + m0 + 16 + cr + g) * H;
        ctxb[row0 + n0 + cc]      = f2b(acc00[g]);
        ctxb[row0 + n0 + 16 + cc] = f2b(acc01[g]);
        ctxb[row1 + n0 + cc]      = f2b(acc10[g]);
        ctxb[row1 + n0 + 16 + cc] = f2b(acc11[g]);
    }
}

// ---- phase 6: pre = tanh([ctx|query] @ W_out^T + b)  (all-bf16 operands) ----
__global__ __launch_bounds__(64) void mfma_out(
    const short* __restrict__ ctxb, const short* __restrict__ qb,
    const short* __restrict__ wob, const float* __restrict__ bias,
    float* __restrict__ pre) {
    const int lane = threadIdx.x;
    const int r = lane & 15, kb = lane >> 4;
    const int m0 = blockIdx.y * 32, n0 = blockIdx.x * 32;
    f32x4 acc00 = {0,0,0,0}, acc01 = {0,0,0,0}, acc10 = {0,0,0,0}, acc11 = {0,0,0,0};
    const short* b0p = wob + (size_t)(n0 + r) * (2 * H) + kb * 8;
    const short* b1p = b0p + 16 * (2 * H);
    {
        const short* a0p = ctxb + (size_t)(m0 + r) * H + kb * 8;
        const short* a1p = a0p + 16 * H;
#pragma unroll 4
        for (int k = 0; k < H; k += 32) MFMA4(a0p, a1p, b0p, b1p, k)
    }
    {
        const short* a0p = qb + (size_t)(m0 + r) * H + kb * 8;
        const short* a1p = a0p + 16 * H;
        const short* c0p = b0p + H;
        const short* c1p = b1p + H;
#pragma unroll 4
        for (int k = 0; k < H; k += 32) MFMA4(a0p, a1p, c0p, c1p, k)
    }
    const int cr = kb * 4, cc = r;
    float bn0 = bias[n0 + cc], bn1 = bias[n0 + 16 + cc];
#pragma unroll
    for (int g = 0; g < 4; ++g) {
        size_t row0 = (size_t)(m0 + cr + g) * H;
        size_t row1 = (size_t)(m0 + 16 + cr + g) * H;
        pre[row0 + n0 + cc]      = fast_tanh(acc00[g] + bn0);
        pre[row0 + n0 + 16 + cc] = fast_tanh(acc01[g] + bn1);
        pre[row1 + n0 + cc]      = fast_tanh(acc10[g] + bn0);
        pre[row1 + n0 + 16 + cc] = fast_tanh(acc11[g] + bn1);
    }
}

// ---- phase 7: per-row LayerNorm ----
__global__ __launch_bounds__(256) void ln_out(
    const float* __restrict__ X, const float* __restrict__ gamma,
    const float* __restrict__ beta, float* __restrict__ out) {
    __shared__ float red[8];
    const int r = blockIdx.x;
    const int tid = threadIdx.x;
    const int lane = tid & 63, wv = tid >> 6;
    const float* x = X + (size_t)r * H;
    float x0 = x[tid], x1 = x[tid + 256];
    float s = x0 + x1;
#pragma unroll
    for (int off = 32; off > 0; off >>= 1) s += __shfl_down(s, off);
    if (lane == 0) red[wv] = s;
    __syncthreads();
    float mu = (red[0] + red[1] + red[2] + red[3]) * (1.0f / H);
    float d0 = x0 - mu, d1 = x1 - mu;
    float vsum = d0 * d0 + d1 * d1;
#pragma unroll
    for (int off = 32; off > 0; off >>= 1) vsum += __shfl_down(vsum, off);
    if (lane == 0) red[4 + wv] = vsum;
    __syncthreads();
    float var = (red[4] + red[5] + red[6] + red[7]) * (1.0f / H);
    float inv = rsqrtf(var + 1e-5f);
    out[(size_t)r * H + tid] = d0 * inv * gamma[tid] + beta[tid];
    out[(size_t)r * H + tid + 256] = d1 * inv * gamma[tid + 256] + beta[tid + 256];
}

extern "C" void kernel_launch(void* const* d_in, const int* in_sizes, int n_in,
                              void* d_out, int out_size, void* d_ws, size_t ws_size,
                              hipStream_t stream) {
    const float* query = (const float*)d_in[0];
    const float* enc   = (const float*)d_in[1];
    const int*   slen  = (const int*)d_in[2];
    const float* W_h   = (const float*)d_in[3];
    const float* W_s   = (const float*)d_in[4];
    const float* v     = (const float*)d_in[5];
    const float* W_out = (const float*)d_in[6];
    const float* b_out = (const float*)d_in[7];
    const float* gamma = (const float*)d_in[8];
    const float* beta  = (const float*)d_in[9];
    float* out = (float*)d_out;

    // ---- workspace map, non-aliased (d_ws = 256 MB) ----
    char* base = (char*)d_ws;
    short* qb     = (short*)(base + 0);          // 512K  bf16 query
    short* wsb    = (short*)(base + 524288);     // 512K  bf16 W_s
    short* whb    = (short*)(base + 1048576);    // 512K  bf16 W_h
    short* wob    = (short*)(base + 1572864);    // 1M    bf16 W_out
    short* eb     = (short*)(base + 2621440);    // 2M    bf16 enc
    float* qe     = (float*)(base + 4718592);    // 1M    f32 exp2(q_proj~)
    float* ke     = (float*)(base + 5767168);    // 4M    f32 exp2(k_proj~)
    float* scoreh = (float*)(base + 9961472);    // 4M    f32 score quarters
    short* attnb  = (short*)(base + 14155776);   // 512K  bf16 attn
    short* encT   = (short*)(base + 14680064);   // 2M    bf16 enc^T
    short* ctxb   = (short*)(base + 16777216);   // 512K  bf16 ctx
    float* pre    = (float*)(base + 17301504);   // 1M    f32 pre-LN

    // cvt (1152 blocks) + encT transpose (1024 blocks, masked tiles skipped)
    cvt_all<<<dim3(2176), dim3(256), 0, stream>>>(query, W_s, W_h, W_out, enc, slen,
                                                  qb, wsb, whb, wob, eb, encT);
    mfma_proj<<<dim3(16, 80), dim3(64), 0, stream>>>(qb, eb, wsb, whb, slen, qe, ke);
    // score quarters: grid (s-tiles=32, t-tiles=16, b*4 quarters=16)
    score_v4<<<dim3(32, 16, 16), dim3(64), 0, stream>>>(qe, ke, v, slen, scoreh);
    softmax_k<<<dim3(B * T), dim3(256), 0, stream>>>(scoreh, slen, attnb);
    mfma_ctx<<<dim3(16, 4, 4), dim3(64), 0, stream>>>(attnb, encT, slen, ctxb);
    mfma_out<<<dim3(16, 16), dim3(64), 0, stream>>>(ctxb, qb, wob, b_out, pre);
    ln_out<<<dim3(B * T), dim3(256), 0, stream>>>(pre, gamma, beta, out);
}